// Round 1
// baseline (595.212 us; speedup 1.0000x reference)
//
#include <hip/hip_runtime.h>
#include <hip/hip_bf16.h>
#include <math.h>

// Problem: q [4,2048,1024] f32, k [8192,1024] f32, v [8192,1024] f32
// scores = q@k^T  [8192 x 8192]; x = scores/||row||*sqrt(8192); gated = gelu_exact(x)
// out = gated @ v  [8192 x 1024] f32.
//
// Strategy: bf16 MFMA for both GEMMs (threshold 3.4e-2 permits bf16 internals).
// ws layout (needs ~176 MiB):
//   [0,16M)    qb   bf16 8192x1024
//   [16M,32M)  kb   bf16 8192x1024
//   [32M,48M)  vbT  bf16 1024x8192   (v transposed so GEMM2 is B^T-form)
//   [48M,176M) scores/gated bf16 8192x8192 (in-place gelu)
//   [176M,+32K) scale f32 [8192]

#define MROWS 8192
#define DIN   1024
#define NBANK 8192
#define DOUT  1024

typedef float  f32x4  __attribute__((ext_vector_type(4)));
typedef __bf16 bf16x8 __attribute__((ext_vector_type(8)));

__device__ __forceinline__ float bf2f(unsigned short u) {
  union { unsigned int i; float f; } x; x.i = ((unsigned int)u) << 16; return x.f;
}
__device__ __forceinline__ unsigned short f2bf(float f) {
  union { float f; unsigned int i; } x; x.f = f;
  unsigned int u = x.i;
  unsigned int r = (u + 0x7fffu + ((u >> 16) & 1u)) >> 16;  // RNE
  return (unsigned short)r;
}

// ---------------- fp32 -> bf16 convert (n divisible by 4) ----------------
__global__ void cvt_kernel(const float* __restrict__ src,
                           unsigned short* __restrict__ dst, int n) {
  int i = (blockIdx.x * 256 + threadIdx.x) * 4;
  if (i >= n) return;
  float4 vv = *(const float4*)(src + i);
  ushort4 o;
  o.x = f2bf(vv.x); o.y = f2bf(vv.y); o.z = f2bf(vv.z); o.w = f2bf(vv.w);
  *(ushort4*)(dst + i) = o;
}

// ---------------- transpose + convert: src[R][C] f32 -> dst[C][R] bf16 ----------------
__global__ void transpose_cvt_kernel(const float* __restrict__ src,
                                     unsigned short* __restrict__ dst,
                                     int R, int C) {
  __shared__ float tile[32][33];  // +1 pad breaks bank conflicts
  int c0 = blockIdx.x * 32, r0 = blockIdx.y * 32;
  for (int i = threadIdx.y; i < 32; i += 8)
    tile[i][threadIdx.x] = src[(size_t)(r0 + i) * C + c0 + threadIdx.x];
  __syncthreads();
  for (int i = threadIdx.y; i < 32; i += 8)
    dst[(size_t)(c0 + i) * R + r0 + threadIdx.x] = f2bf(tile[threadIdx.x][i]);
}

// ---------------- B^T GEMM: C[M][N] = A[M][K] * B[N][K]^T (all bf16 in, f32 acc) ----
// m97 structure: 128x128 block tile, 256 threads = 4 waves, each wave 64x64 via
// 4x4 grid of 16x16x32 MFMA; BK=32; global_load_lds width=16 staging.
template <bool OUT_BF16>
__global__ __launch_bounds__(256, 2) void gemm_bt_kernel(
    const unsigned short* __restrict__ A, const unsigned short* __restrict__ B,
    void* __restrict__ C, int K, int ldc) {
  __shared__ unsigned short As[128 * 32];  // [row][k], 8 KiB
  __shared__ unsigned short Bs[128 * 32];

  const int tid  = threadIdx.x;
  const int lane = tid & 63;
  const int wave = tid >> 6;
  const int wm   = (wave >> 1) * 64;  // wave tile row origin in block
  const int wn   = (wave & 1) * 64;   // wave tile col origin
  const int quad = lane >> 4;
  const int l16  = lane & 15;

  const size_t m0 = (size_t)blockIdx.y * 128;
  const size_t n0 = (size_t)blockIdx.x * 128;

  // staging: thread t loads 16B (8 bf16) at tile row t/4, k-col (t%4)*8.
  // LDS dst offset = t*16 bytes -> wave-uniform base + lane*16 (global_load_lds req).
  const int srow = tid >> 2;
  const int scol = (tid & 3) * 8;
  const unsigned short* Ag0 = A + (m0 + srow) * (size_t)K + scol;
  const unsigned short* Ag1 = A + (m0 + srow + 64) * (size_t)K + scol;
  const unsigned short* Bg0 = B + (n0 + srow) * (size_t)K + scol;
  const unsigned short* Bg1 = B + (n0 + srow + 64) * (size_t)K + scol;

  unsigned short* AsW0 = As + tid * 8;
  unsigned short* AsW1 = As + 64 * 32 + tid * 8;
  unsigned short* BsW0 = Bs + tid * 8;
  unsigned short* BsW1 = Bs + 64 * 32 + tid * 8;

  // LDS read base: A-frag for tile i = As[(wm + i*16 + l16)*32 + quad*8], 8 contiguous
  const unsigned short* ArP = As + (wm + l16) * 32 + quad * 8;
  const unsigned short* BrP = Bs + (wn + l16) * 32 + quad * 8;

  f32x4 acc[4][4];
#pragma unroll
  for (int i = 0; i < 4; i++)
#pragma unroll
    for (int j = 0; j < 4; j++) {
      f32x4 z = {0.f, 0.f, 0.f, 0.f};
      acc[i][j] = z;
    }

  for (int k0 = 0; k0 < K; k0 += 32) {
    __builtin_amdgcn_global_load_lds(
        (const __attribute__((address_space(1))) unsigned int*)(Ag0 + k0),
        (__attribute__((address_space(3))) unsigned int*)AsW0, 16, 0, 0);
    __builtin_amdgcn_global_load_lds(
        (const __attribute__((address_space(1))) unsigned int*)(Ag1 + k0),
        (__attribute__((address_space(3))) unsigned int*)AsW1, 16, 0, 0);
    __builtin_amdgcn_global_load_lds(
        (const __attribute__((address_space(1))) unsigned int*)(Bg0 + k0),
        (__attribute__((address_space(3))) unsigned int*)BsW0, 16, 0, 0);
    __builtin_amdgcn_global_load_lds(
        (const __attribute__((address_space(1))) unsigned int*)(Bg1 + k0),
        (__attribute__((address_space(3))) unsigned int*)BsW1, 16, 0, 0);
    __syncthreads();  // drains vmcnt, makes staged tiles visible

    bf16x8 af[4], bfr[4];
#pragma unroll
    for (int i = 0; i < 4; i++) af[i] = *(const bf16x8*)(ArP + i * 16 * 32);
#pragma unroll
    for (int j = 0; j < 4; j++) bfr[j] = *(const bf16x8*)(BrP + j * 16 * 32);
#pragma unroll
    for (int i = 0; i < 4; i++)
#pragma unroll
      for (int j = 0; j < 4; j++)
        acc[i][j] = __builtin_amdgcn_mfma_f32_16x16x32_bf16(af[i], bfr[j],
                                                            acc[i][j], 0, 0, 0);
    __syncthreads();  // all waves done reading before next stage overwrites
  }

  // Epilogue. C/D layout (m89/m91): col = lane&15, row = (lane>>4)*4 + reg.
#pragma unroll
  for (int i = 0; i < 4; i++)
#pragma unroll
    for (int j = 0; j < 4; j++)
#pragma unroll
      for (int r = 0; r < 4; r++) {
        size_t row = m0 + wm + i * 16 + quad * 4 + r;
        size_t col = n0 + wn + j * 16 + l16;
        float val = acc[i][j][r];
        if (OUT_BF16)
          ((unsigned short*)C)[row * (size_t)ldc + col] = f2bf(val);
        else
          ((float*)C)[row * (size_t)ldc + col] = val;
      }
}

// ---------------- per-row scale = sqrt(N) / ||row||_2 ----------------
__global__ void rownorm_kernel(const unsigned short* __restrict__ S,
                               float* __restrict__ scale) {
  __shared__ float red[4];
  const int row = blockIdx.x;
  const unsigned short* p = S + (size_t)row * NBANK;
  float sum = 0.f;
  for (int c = threadIdx.x * 8; c < NBANK; c += 256 * 8) {
    uint4 vv = *(const uint4*)(p + c);
    unsigned int w[4] = {vv.x, vv.y, vv.z, vv.w};
#pragma unroll
    for (int e = 0; e < 4; e++) {
      float f0 = bf2f((unsigned short)(w[e] & 0xffffu));
      float f1 = bf2f((unsigned short)(w[e] >> 16));
      sum += f0 * f0 + f1 * f1;
    }
  }
#pragma unroll
  for (int off = 32; off > 0; off >>= 1) sum += __shfl_down(sum, off, 64);
  if ((threadIdx.x & 63) == 0) red[threadIdx.x >> 6] = sum;
  __syncthreads();
  if (threadIdx.x == 0) {
    float t = red[0] + red[1] + red[2] + red[3];
    scale[row] = sqrtf((float)NBANK) / sqrtf(t);
  }
}

// ---------------- in-place exact GELU(x * scale[row]) ----------------
__global__ void gelu_kernel(unsigned short* __restrict__ S,
                            const float* __restrict__ scale) {
  size_t idx = ((size_t)blockIdx.x * 256 + threadIdx.x) * 8;
  int row = (int)(idx >> 13);  // / 8192
  float sc = scale[row];
  uint4 vv = *(const uint4*)(S + idx);
  unsigned int w[4] = {vv.x, vv.y, vv.z, vv.w};
#pragma unroll
  for (int e = 0; e < 4; e++) {
    float x0 = bf2f((unsigned short)(w[e] & 0xffffu)) * sc;
    float x1 = bf2f((unsigned short)(w[e] >> 16)) * sc;
    float g0 = 0.5f * x0 * (1.0f + erff(x0 * 0.70710678118654752f));
    float g1 = 0.5f * x1 * (1.0f + erff(x1 * 0.70710678118654752f));
    w[e] = (unsigned int)f2bf(g0) | ((unsigned int)f2bf(g1) << 16);
  }
  uint4 o; o.x = w[0]; o.y = w[1]; o.z = w[2]; o.w = w[3];
  *(uint4*)(S + idx) = o;
}

extern "C" void kernel_launch(void* const* d_in, const int* in_sizes, int n_in,
                              void* d_out, int out_size, void* d_ws, size_t ws_size,
                              hipStream_t stream) {
  const float* q = (const float*)d_in[0];
  const float* k = (const float*)d_in[1];
  const float* v = (const float*)d_in[2];
  float* out = (float*)d_out;

  char* ws = (char*)d_ws;
  const size_t MB = 1024ull * 1024ull;
  unsigned short* qb     = (unsigned short*)(ws);
  unsigned short* kb     = (unsigned short*)(ws + 16 * MB);
  unsigned short* vbT    = (unsigned short*)(ws + 32 * MB);
  unsigned short* scores = (unsigned short*)(ws + 48 * MB);
  float*          scale  = (float*)(ws + 176 * MB);
  // requires ws_size >= 176 MiB + 32 KiB

  const int nqk = MROWS * DIN;  // 8388608, same for q and k

  cvt_kernel<<<nqk / 1024, 256, 0, stream>>>(q, qb, nqk);
  cvt_kernel<<<nqk / 1024, 256, 0, stream>>>(k, kb, nqk);
  transpose_cvt_kernel<<<dim3(DOUT / 32, NBANK / 32), dim3(32, 8), 0, stream>>>(
      v, vbT, NBANK, DOUT);

  // GEMM1: scores[8192][8192] = qb[8192][1024] @ kb[8192][1024]^T  (bf16 out)
  gemm_bt_kernel<true><<<dim3(NBANK / 128, MROWS / 128), 256, 0, stream>>>(
      qb, kb, scores, DIN, NBANK);

  rownorm_kernel<<<MROWS, 256, 0, stream>>>(scores, scale);

  gelu_kernel<<<(MROWS * (size_t)NBANK) / (256 * 8), 256, 0, stream>>>(scores, scale);

  // GEMM2: out[8192][1024] = gated[8192][8192] @ vbT[1024][8192]^T  (f32 out)
  gemm_bt_kernel<false><<<dim3(DOUT / 128, MROWS / 128), 256, 0, stream>>>(
      scores, vbT, out, NBANK, DOUT);
}

// Round 2
// 560.004 us; speedup vs baseline: 1.0629x; 1.0629x over previous
//
#include <hip/hip_runtime.h>
#include <hip/hip_bf16.h>
#include <math.h>

// q [8192,1024] f32, k [8192,1024] f32, v [8192,1024] f32
// scores = q@k^T; x = scores/||row|| * sqrt(8192); gated = gelu_exact(x); out = gated@v
//
// ws layout (~176 MiB):
//   [0,16M)    qb   bf16 8192x1024
//   [16M,32M)  kb   bf16 8192x1024
//   [32M,48M)  vbT  bf16 1024x8192
//   [48M,176M) scores/gated bf16 8192x8192 (in-place gelu)
//   [176M,+32K) sumsq->scale f32 [8192]

#define MROWS 8192
#define DIN   1024
#define NBANK 8192
#define DOUT  1024

typedef float  f32x4  __attribute__((ext_vector_type(4)));
typedef __bf16 bf16x8 __attribute__((ext_vector_type(8)));

__device__ __forceinline__ float bf2f(unsigned short u) {
  union { unsigned int i; float f; } x; x.i = ((unsigned int)u) << 16; return x.f;
}
__device__ __forceinline__ unsigned short f2bf(float f) {
  union { float f; unsigned int i; } x; x.f = f;
  unsigned int u = x.i;
  unsigned int r = (u + 0x7fffu + ((u >> 16) & 1u)) >> 16;  // RNE
  return (unsigned short)r;
}

// ---------------- fp32 -> bf16 convert ----------------
__global__ void cvt_kernel(const float* __restrict__ src,
                           unsigned short* __restrict__ dst, int n) {
  int i = (blockIdx.x * 256 + threadIdx.x) * 4;
  if (i >= n) return;
  float4 vv = *(const float4*)(src + i);
  ushort4 o;
  o.x = f2bf(vv.x); o.y = f2bf(vv.y); o.z = f2bf(vv.z); o.w = f2bf(vv.w);
  *(ushort4*)(dst + i) = o;
}

// ---------------- transpose + convert: src[R][C] f32 -> dst[C][R] bf16 ----------------
__global__ void transpose_cvt_kernel(const float* __restrict__ src,
                                     unsigned short* __restrict__ dst,
                                     int R, int C) {
  __shared__ float tile[32][33];
  int c0 = blockIdx.x * 32, r0 = blockIdx.y * 32;
  for (int i = threadIdx.y; i < 32; i += 8)
    tile[i][threadIdx.x] = src[(size_t)(r0 + i) * C + c0 + threadIdx.x];
  __syncthreads();
  for (int i = threadIdx.y; i < 32; i += 8)
    dst[(size_t)(c0 + i) * R + r0 + threadIdx.x] = f2bf(tile[threadIdx.x][i]);
}

// ---------------- zero fill (float4 granularity) ----------------
__global__ void zero_f32_kernel(float* __restrict__ p, int n4) {
  int i = blockIdx.x * 256 + threadIdx.x;
  if (i < n4) ((float4*)p)[i] = make_float4(0.f, 0.f, 0.f, 0.f);
}

// ---------------- GEMM1: scores = qb @ kb^T (bf16 out) + row sumsq atomics ----------
__global__ __launch_bounds__(256, 2) void gemm1_kernel(
    const unsigned short* __restrict__ A, const unsigned short* __restrict__ B,
    unsigned short* __restrict__ C, float* __restrict__ sumsq) {
  __shared__ unsigned short As[128 * 32];
  __shared__ unsigned short Bs[128 * 32];
  const int K = DIN, ldc = NBANK;

  const int tid  = threadIdx.x;
  const int lane = tid & 63;
  const int wave = tid >> 6;
  const int wm   = (wave >> 1) * 64;
  const int wn   = (wave & 1) * 64;
  const int quad = lane >> 4;
  const int l16  = lane & 15;

  const size_t m0 = (size_t)blockIdx.y * 128;
  const size_t n0 = (size_t)blockIdx.x * 128;

  const int srow = tid >> 2;
  const int scol = (tid & 3) * 8;
  const unsigned short* Ag0 = A + (m0 + srow) * (size_t)K + scol;
  const unsigned short* Ag1 = A + (m0 + srow + 64) * (size_t)K + scol;
  const unsigned short* Bg0 = B + (n0 + srow) * (size_t)K + scol;
  const unsigned short* Bg1 = B + (n0 + srow + 64) * (size_t)K + scol;

  unsigned short* AsW0 = As + tid * 8;
  unsigned short* AsW1 = As + 64 * 32 + tid * 8;
  unsigned short* BsW0 = Bs + tid * 8;
  unsigned short* BsW1 = Bs + 64 * 32 + tid * 8;

  const unsigned short* ArP = As + (wm + l16) * 32 + quad * 8;
  const unsigned short* BrP = Bs + (wn + l16) * 32 + quad * 8;

  f32x4 acc[4][4];
#pragma unroll
  for (int i = 0; i < 4; i++)
#pragma unroll
    for (int j = 0; j < 4; j++) {
      f32x4 z = {0.f, 0.f, 0.f, 0.f};
      acc[i][j] = z;
    }

  for (int k0 = 0; k0 < K; k0 += 32) {
    __builtin_amdgcn_global_load_lds(
        (const __attribute__((address_space(1))) unsigned int*)(Ag0 + k0),
        (__attribute__((address_space(3))) unsigned int*)AsW0, 16, 0, 0);
    __builtin_amdgcn_global_load_lds(
        (const __attribute__((address_space(1))) unsigned int*)(Ag1 + k0),
        (__attribute__((address_space(3))) unsigned int*)AsW1, 16, 0, 0);
    __builtin_amdgcn_global_load_lds(
        (const __attribute__((address_space(1))) unsigned int*)(Bg0 + k0),
        (__attribute__((address_space(3))) unsigned int*)BsW0, 16, 0, 0);
    __builtin_amdgcn_global_load_lds(
        (const __attribute__((address_space(1))) unsigned int*)(Bg1 + k0),
        (__attribute__((address_space(3))) unsigned int*)BsW1, 16, 0, 0);
    __syncthreads();

    bf16x8 af[4], bfr[4];
#pragma unroll
    for (int i = 0; i < 4; i++) af[i] = *(const bf16x8*)(ArP + i * 16 * 32);
#pragma unroll
    for (int j = 0; j < 4; j++) bfr[j] = *(const bf16x8*)(BrP + j * 16 * 32);
#pragma unroll
    for (int i = 0; i < 4; i++)
#pragma unroll
      for (int j = 0; j < 4; j++)
        acc[i][j] = __builtin_amdgcn_mfma_f32_16x16x32_bf16(af[i], bfr[j],
                                                            acc[i][j], 0, 0, 0);
    __syncthreads();
  }

  // Epilogue: store bf16 scores + per-row sum-of-squares (f32 acc) via atomics.
#pragma unroll
  for (int i = 0; i < 4; i++)
#pragma unroll
    for (int r = 0; r < 4; r++) {
      size_t row = m0 + wm + i * 16 + quad * 4 + r;
      float s = 0.f;
#pragma unroll
      for (int j = 0; j < 4; j++) {
        float val = acc[i][j][r];
        s += val * val;
        C[row * (size_t)ldc + n0 + wn + j * 16 + l16] = f2bf(val);
      }
      // reduce across the 16 lanes (same quad) sharing this row
      s += __shfl_xor(s, 1);
      s += __shfl_xor(s, 2);
      s += __shfl_xor(s, 4);
      s += __shfl_xor(s, 8);
      if (l16 == 0) atomicAdd(&sumsq[row], s);
    }
}

// ---------------- scale = sqrt(N / sumsq), in place ----------------
__global__ void finalize_scale_kernel(float* __restrict__ s) {
  int i = blockIdx.x * 256 + threadIdx.x;
  if (i < MROWS) s[i] = sqrtf((float)NBANK / s[i]);
}

// ---------------- in-place exact GELU(x * scale[row]) ----------------
__global__ void gelu_kernel(unsigned short* __restrict__ S,
                            const float* __restrict__ scale) {
  size_t idx = ((size_t)blockIdx.x * 256 + threadIdx.x) * 8;
  int row = (int)(idx >> 13);
  float sc = scale[row];
  uint4 vv = *(const uint4*)(S + idx);
  unsigned int w[4] = {vv.x, vv.y, vv.z, vv.w};
#pragma unroll
  for (int e = 0; e < 4; e++) {
    float x0 = bf2f((unsigned short)(w[e] & 0xffffu)) * sc;
    float x1 = bf2f((unsigned short)(w[e] >> 16)) * sc;
    float g0 = 0.5f * x0 * (1.0f + erff(x0 * 0.70710678118654752f));
    float g1 = 0.5f * x1 * (1.0f + erff(x1 * 0.70710678118654752f));
    w[e] = (unsigned int)f2bf(g0) | ((unsigned int)f2bf(g1) << 16);
  }
  uint4 o; o.x = w[0]; o.y = w[1]; o.z = w[2]; o.w = w[3];
  *(uint4*)(S + idx) = o;
}

// ---------------- GEMM2: out += gated @ vbT^T, 128x256 tile, split-K x2 --------------
// 512 threads = 8 waves in 2x4 grid of 64x64 wave tiles. f32 atomic accumulate.
__global__ __launch_bounds__(512, 4) void gemm2_kernel(
    const unsigned short* __restrict__ A,   // gated [8192][8192]
    const unsigned short* __restrict__ B,   // vbT   [1024][8192]
    float* __restrict__ C) {                // out   [8192][1024], pre-zeroed
  __shared__ unsigned short As[128 * 32];   //  8 KiB
  __shared__ unsigned short Bs[256 * 32];   // 16 KiB
  const int K = NBANK, ldc = DOUT;

  const int tid  = threadIdx.x;
  const int lane = tid & 63;
  const int wave = tid >> 6;          // 0..7
  const int wm   = (wave >> 2) * 64;  // 0,64
  const int wn   = (wave & 3) * 64;   // 0,64,128,192
  const int quad = lane >> 4;
  const int l16  = lane & 15;

  const size_t m0 = (size_t)blockIdx.y * 128;
  const size_t n0 = (size_t)blockIdx.x * 256;
  const int    ks = blockIdx.z * (K / 2);   // split-K

  const int srow = tid >> 2;          // 0..127
  const int scol = (tid & 3) * 8;
  const unsigned short* Ag  = A + (m0 + srow) * (size_t)K + scol + ks;
  const unsigned short* Bg0 = B + (n0 + srow) * (size_t)K + scol + ks;
  const unsigned short* Bg1 = B + (n0 + srow + 128) * (size_t)K + scol + ks;

  unsigned short* AsW  = As + tid * 8;
  unsigned short* BsW0 = Bs + tid * 8;
  unsigned short* BsW1 = Bs + 512 * 8 + tid * 8;

  const unsigned short* ArP = As + (wm + l16) * 32 + quad * 8;
  const unsigned short* BrP = Bs + (wn + l16) * 32 + quad * 8;

  f32x4 acc[4][4];
#pragma unroll
  for (int i = 0; i < 4; i++)
#pragma unroll
    for (int j = 0; j < 4; j++) {
      f32x4 z = {0.f, 0.f, 0.f, 0.f};
      acc[i][j] = z;
    }

  for (int k0 = 0; k0 < K / 2; k0 += 32) {
    __builtin_amdgcn_global_load_lds(
        (const __attribute__((address_space(1))) unsigned int*)(Ag + k0),
        (__attribute__((address_space(3))) unsigned int*)AsW, 16, 0, 0);
    __builtin_amdgcn_global_load_lds(
        (const __attribute__((address_space(1))) unsigned int*)(Bg0 + k0),
        (__attribute__((address_space(3))) unsigned int*)BsW0, 16, 0, 0);
    __builtin_amdgcn_global_load_lds(
        (const __attribute__((address_space(1))) unsigned int*)(Bg1 + k0),
        (__attribute__((address_space(3))) unsigned int*)BsW1, 16, 0, 0);
    __syncthreads();

    bf16x8 af[4], bfr[4];
#pragma unroll
    for (int i = 0; i < 4; i++) af[i] = *(const bf16x8*)(ArP + i * 16 * 32);
#pragma unroll
    for (int j = 0; j < 4; j++) bfr[j] = *(const bf16x8*)(BrP + j * 16 * 32);
#pragma unroll
    for (int i = 0; i < 4; i++)
#pragma unroll
      for (int j = 0; j < 4; j++)
        acc[i][j] = __builtin_amdgcn_mfma_f32_16x16x32_bf16(af[i], bfr[j],
                                                            acc[i][j], 0, 0, 0);
    __syncthreads();
  }

#pragma unroll
  for (int i = 0; i < 4; i++)
#pragma unroll
    for (int j = 0; j < 4; j++)
#pragma unroll
      for (int r = 0; r < 4; r++) {
        size_t row = m0 + wm + i * 16 + quad * 4 + r;
        size_t col = n0 + wn + j * 16 + l16;
        atomicAdd(&C[row * (size_t)ldc + col], acc[i][j][r]);
      }
}

extern "C" void kernel_launch(void* const* d_in, const int* in_sizes, int n_in,
                              void* d_out, int out_size, void* d_ws, size_t ws_size,
                              hipStream_t stream) {
  const float* q = (const float*)d_in[0];
  const float* k = (const float*)d_in[1];
  const float* v = (const float*)d_in[2];
  float* out = (float*)d_out;

  char* ws = (char*)d_ws;
  const size_t MB = 1024ull * 1024ull;
  unsigned short* qb     = (unsigned short*)(ws);
  unsigned short* kb     = (unsigned short*)(ws + 16 * MB);
  unsigned short* vbT    = (unsigned short*)(ws + 32 * MB);
  unsigned short* scores = (unsigned short*)(ws + 48 * MB);
  float*          scale  = (float*)(ws + 176 * MB);  // sumsq, then scale in place

  const int nqk = MROWS * DIN;

  // zero out (atomic accumulate target) and sumsq
  zero_f32_kernel<<<(MROWS * DOUT / 4 + 255) / 256, 256, 0, stream>>>(out,
                                                                      MROWS * DOUT / 4);
  zero_f32_kernel<<<(MROWS / 4 + 255) / 256, 256, 0, stream>>>(scale, MROWS / 4);

  cvt_kernel<<<nqk / 1024, 256, 0, stream>>>(q, qb, nqk);
  cvt_kernel<<<nqk / 1024, 256, 0, stream>>>(k, kb, nqk);
  transpose_cvt_kernel<<<dim3(DOUT / 32, NBANK / 32), dim3(32, 8), 0, stream>>>(
      v, vbT, NBANK, DOUT);

  gemm1_kernel<<<dim3(NBANK / 128, MROWS / 128), 256, 0, stream>>>(qb, kb, scores,
                                                                   scale);

  finalize_scale_kernel<<<MROWS / 256, 256, 0, stream>>>(scale);

  gelu_kernel<<<(MROWS * (size_t)NBANK) / (256 * 8), 256, 0, stream>>>(scores, scale);

  gemm2_kernel<<<dim3(DOUT / 256, MROWS / 128, 2), 512, 0, stream>>>(scores, vbT, out);
}